// Round 7
// baseline (1028.990 us; speedup 1.0000x reference)
//
#include <hip/hip_runtime.h>
#include <math.h>

// Bayesian 2-layer LSTM (B=8192,T=100,I=24,H=64,H2=128) — two-kernel version.
//
// R12: 16-wave restructure of R8 (R11's W1-hoist spilled: WRITE_SIZE 32K->2.6M,
// reverted). R8 diagnosis: 2 lockstep waves/SIMD -> serial trans chains leave
// ~30% SIMD idle. Change: 1024 threads/block (16 waves), same 256 blocks x 32
// rows. L2 output split 16 ways: wave w owns (m=w&1, colgroup=w>>1) -> W2
// slice 12 frags = 48 regs (was 96), L2 acc 16 regs (was 32), L2 pointwise 4
// elems/thread (was 8). L1 stays on waves 0-7 exactly as R8 (W1 from LDS);
// waves 8-15 take the x load/store. 4 waves/SIMD (2 heavy + 2 light each):
// same VALU work per SIMD, 2x waves to hide trans latency.
// Reg discipline for the 128-cap at 4 waves/EU: biases re-read from LDS each
// step (-8 persistent), last-step h2 written through to LDS fp32 (-4, deletes
// head H2-copy), heavy waves carry no x regs.

typedef __attribute__((ext_vector_type(8))) short short8;   // 8 bf16
typedef __attribute__((ext_vector_type(4))) float f32x4;

#define MFMA16(a, b, c) __builtin_amdgcn_mfma_f32_16x16x32_bf16((a), (b), (c), 0, 0, 0)

// ---- d_ws layout (bytes) ----
// [0, 196608)        W2S : 12288 short8 frags, idx = (kk*4+g)*512 + tid
// [196608, 245760)   W1G : 3072 short8, u = slice*256+n (slice = kk*4+quad)
// [245760, 253284)   WF  : 1881 floats: b1[256] b2[512] fc1w[1024] fc2w[64]
//                          fc1b[8] fc2b[8] ow[8] ob[1]
#define WS_W1G_OFF 196608
#define WS_WF_OFF  245760

struct SampParams {
  const float* w1i[3]; const float* w1h[3]; const float* b1[3];
  const float* w2i[3]; const float* w2h[3]; const float* b2[3];
  const float* f1w[3]; const float* f1b[3];
  const float* f2w[3]; const float* f2b[3];
  const float* ow[3];  const float* ob[3];
  short* W2S; short* W1G; float* WF;
};

struct LstmParams {
  const float* input;
  const short* W2S; const short* W1G; const float* WF;
  float* out;
};

__device__ __forceinline__ float softplus_fast(float x) {
  float e = __builtin_amdgcn_exp2f(1.44269504f * x);
  return 0.69314718f * __builtin_amdgcn_logf(1.0f + e);
}

__device__ __forceinline__ float samp(const float* const q[3], int idx) {
  return q[0][idx] + softplus_fast(q[1][idx]) * q[2][idx];
}

__device__ __forceinline__ short f2bf(float f) {
  unsigned u = __float_as_uint(f);
  unsigned r = (u + 0x7FFFu + ((u >> 16) & 1u)) >> 16;   // RNE
  return (short)r;
}

__device__ __forceinline__ unsigned cvt_pk_bf16(float lo, float hi) {
  unsigned r;
  asm("v_cvt_pk_bf16_f32 %0, %1, %2" : "=v"(r) : "v"(lo), "v"(hi));
  return r;
}

// One LSTM element: gates (i,f,g,o) -> new cell c, hidden h.
// rcp(A)&rcp(B) via r=rcp(A*B): 1/A=r*B, 1/B=r*A.  5 exp2 + 3 rcp.  (R8)
__device__ __forceinline__ void lstm_elem(float gi, float gf, float gg, float go,
                                          float& c, float& h) {
  float A = 1.0f + __builtin_amdgcn_exp2f(-1.44269504f * gi);   // 1/A = sig(i)
  float B = 1.0f + __builtin_amdgcn_exp2f(-1.44269504f * gf);   // 1/B = sig(f)
  float r = __builtin_amdgcn_rcpf(A * B);
  float si = r * B;
  float sf = r * A;
  float C = 1.0f + __builtin_amdgcn_exp2f(2.88539008f * gg);    // tanh(g)=1-2/C
  float D = 1.0f + __builtin_amdgcn_exp2f(-1.44269504f * go);   // 1/D = sig(o)
  float r2 = __builtin_amdgcn_rcpf(C * D);
  float tg = 1.0f - 2.0f * (r2 * D);
  float so = r2 * C;
  float cn = sf * c + si * tg;
  c = cn;
  float E = 1.0f + __builtin_amdgcn_exp2f(2.88539008f * cn);
  h = so * (1.0f - 2.0f * __builtin_amdgcn_rcpf(E));
}

// ---------------- kernel 1: sample all weights into d_ws ----------------
__global__ __launch_bounds__(256) void sample_kernel(SampParams p)
{
  int i = blockIdx.x * 256 + threadIdx.x;
  if (i < 12288) {
    int tid = i & 511, gg = (i >> 9) & 3, kk = i >> 11;
    int quad = (tid >> 4) & 3, col = tid & 15, v0 = (tid >> 6) * 16;
    int c = gg * 128 + v0 + col;
    short8 v;
#pragma unroll
    for (int j = 0; j < 8; ++j) {
      int k = kk * 32 + quad * 8 + j;
      float x = (k < 64) ? samp(p.w2i, k * 512 + c) : samp(p.w2h, (k - 64) * 512 + c);
      v[j] = f2bf(x);
    }
    *(short8*)&p.W2S[i * 8] = v;
  } else if (i < 15360) {
    int u = i - 12288;
    int slice = u >> 8, n = u & 255;
    int k0 = (slice >> 2) * 32 + (slice & 3) * 8;
    short8 v;
#pragma unroll
    for (int j = 0; j < 8; ++j) {
      int k = k0 + j;
      float x = 0.0f;
      if (k < 24)       x = samp(p.w1i, k * 256 + n);
      else if (k >= 32) x = samp(p.w1h, (k - 32) * 256 + n);
      v[j] = f2bf(x);
    }
    *(short8*)&p.W1G[u * 8] = v;
  } else if (i < 17241) {
    int u = i - 15360;
    float x;
    if (u < 256)       x = samp(p.b1,  u);
    else if (u < 768)  x = samp(p.b2,  u - 256);
    else if (u < 1792) x = samp(p.f1w, u - 768);
    else if (u < 1856) x = samp(p.f2w, u - 1792);
    else if (u < 1864) x = samp(p.f1b, u - 1856);
    else if (u < 1872) x = samp(p.f2b, u - 1864);
    else if (u < 1880) x = samp(p.ow,  u - 1872);
    else               x = samp(p.ob,  0);
    p.WF[u] = x;
  }
}

// ---------------- kernel 2: fused 2-layer LSTM + head ----------------
// LDS pool (99840 B):
//   [0,49152)      W1L : W1cat bf16 (3072 short8)
//   [49152,62464)  A1  : 2 buf x (32 x 104 shorts) [x(24)|pad(8)|h1(64)]
//   [62464,79872)  A2  : 2 buf x (32 x 136 shorts) [h2(128)|pad]
//   [79872,96768)  H2F : 32 x 132 f32 (last-step h2, write-through)
//   [96768,99840)  BIA : 768 f32 (b1[256] b2[512])
// Head aliases W1L region: FC1W@16896, FC2W@20992, FB1/FB2/OW/OB, X1, X2

__global__ __launch_bounds__(1024, 4)
void blstm_kernel(LstmParams p)
{
  __shared__ __align__(16) unsigned char pool[99840];
  short* const W1L = (short*)pool;
  short* const A1b = (short*)(pool + 49152);   // 2 x 3328 shorts
  short* const A2b = (short*)(pool + 62464);   // 2 x 4352 shorts
  float* const H2F = (float*)(pool + 79872);   // 32 x 132 f32
  float* const BIA = (float*)(pool + 96768);   // 768 f32

  const int tid  = threadIdx.x;
  const int w    = tid >> 6;        // 0..15
  const int l    = tid & 63;
  const int quad = l >> 4;
  const int col  = l & 15;
  const int b0   = blockIdx.x * 32;

  const bool hv = (w < 8);          // heavy waves: do layer 1
  const int wq = w & 3;             // layer1: n-group (heavy only)
  const int mh = (w >> 2) & 1;      // layer1: m-half  (heavy only)
  const int m2 = w & 1;             // layer2: m-half
  const int cg = w >> 1;            // layer2: 16-col group (0..7)
  const int u2 = cg * 16 + col;     // layer2: h2 column

  // W2 -> persistent registers: 12 frags = 48 regs (one m-half's B-operands).
  const short8* const W2v = (const short8*)p.W2S;
  short8 w2r[12];
#pragma unroll
  for (int kk = 0; kk < 6; ++kk)
#pragma unroll
    for (int g = 0; g < 2; ++g) {
      // frags for gates 2g..: need all 4 gates -> 6kk x 4g? No: 4 gates, but
      // each frag covers 16 cols of ONE gate: f = kk*4+gate, col-group cg.
    }
  // (loaded explicitly below; loop above is a no-op kept out — see w2r fill)
#pragma unroll
  for (int f = 0; f < 12; ++f) {
    int kk = f / 2;          // placeholder, real fill next
    (void)kk;
  }
  // Real fill: w2r[kk*?]: we need 6 kk x 4 gates = 24 16-col frags for a FULL
  // column set; this wave owns 16 cols per gate -> 6kk x 4g frags of its cg?
  // No: 24 frags again. Correct ownership: each wave owns 16 columns PER GATE
  // -> but L2 acc is g2[4] (4 gates x 16 cols) => frags needed = 6kk x 4g = 24
  // ... halving comes from m-split only in MFMA count, not B-frags. So keep
  // 24 frags but they are SHARED between wave pairs (2cg, 2cg+1) — still 96
  // regs. To truly halve, split gates instead: wave owns 2 gates x 16 cols.
  short8 w2g[12];            // 6 kk x 2 gates (this wave's gate pair)
  const int gp = m2;         // gate-pair selector: gates {gp*2, gp*2+1}
#pragma unroll
  for (int kk = 0; kk < 6; ++kk)
#pragma unroll
    for (int gg = 0; gg < 2; ++gg)
      w2g[kk * 2 + gg] = W2v[(kk * 4 + (gp * 2 + gg)) * 512 + cg * 64 + l];

  // W1 global -> LDS (48 KB), 1024 threads x 3 rounds
#pragma unroll
  for (int r = 0; r < 3; ++r) {
    short8 v = *(const short8*)&p.W1G[(r * 1024 + tid) * 8];
    *(short8*)&W1L[(r * 1024 + tid) * 8] = v;
  }

  // biases -> LDS (re-read per step to save persistent regs)
  if (tid < 768) BIA[tid] = p.WF[tid];

  for (int i = tid; i < 6656; i += 1024) A1b[i] = 0;   // both A1 buffers
  for (int i = tid; i < 8704; i += 1024) A2b[i] = 0;   // both A2 buffers
  __syncthreads();

  // x_0 -> A1 buf0, handled by waves 8-13.x (384 lanes of the light half)
  int xr = 0, xi = 0;
  const int xw = tid - 512;
  const bool xln = (xw >= 0) && (xw < 384);
  const float* xptr = p.input;
  if (xln) {
    int e = xw * 2; xr = e / 24; xi = e - xr * 24;
    const float* base = p.input + (size_t)(b0 + xr) * 2400 + xi;
    float2 xv0 = *(const float2*)base;
    *(unsigned*)&A1b[xr * 104 + xi] = cvt_pk_bf16(xv0.x, xv0.y);
    xptr = base + 24;                 // -> x_1
  }
  __syncthreads();

  float c1a[4]  = {0.f, 0.f, 0.f, 0.f};   // layer1 cells (heavy waves)
  float c2a[4]  = {0.f, 0.f, 0.f, 0.f};   // wait: gate-split => cell split?

  // NOTE on L2 split: with gate-pair ownership a wave computes only 2 of the
  // 4 gates of an element — the pointwise needs all 4. So gate-split is WRONG
  // for pointwise locality. Revert to R8's column ownership (all 4 gates of
  // 16 cols) but m-split the ROWS: wave (m2,cg) computes rows m2*16..+15 of
  // cols cg*16..+15, needing 24 B-frags (all 4 gates) = 96 regs. Wave pair
  // (2cg, 2cg+1) holds identical frags. 96 regs breaks the 128 cap -> instead
  // each wave of the pair holds HALF the kk-range (3 kk = 48 regs) and reads
  // the other 3 kk from W2S via L2 cache (3*4=12 dwordx4 loads/step, the
  // pair's loads hit L2/L3; issue early, consumed late).
  const int kk0 = m2 * 3;                 // this wave's in-reg kk half: kk0..kk0+2
  short8 w2h[12];                         // 3 kk x 4 gates in regs
#pragma unroll
  for (int kk = 0; kk < 3; ++kk)
#pragma unroll
    for (int g = 0; g < 4; ++g)
      w2h[kk * 4 + g] = W2v[((kk + kk0) * 4 + g) * 512 + cg * 64 + l];

  float c2r[4] = {0.f, 0.f, 0.f, 0.f};    // layer2 cells (4 elems/thread)

  const int a1rd = (mh * 16 + col) * 104;

  auto step = [&](const short* __restrict__ A1r, const short* __restrict__ A2r,
                  short* __restrict__ A1w, short* __restrict__ A2w,
                  bool dox, bool last) {
    const bool do_x = dox && xln;
    float2 xv;
    if (do_x) xv = *(const float2*)xptr;   // x_{j+1}

    // ---- issue the streamed W2 half early (other 3 kk, 12 frags) ----
    short8 w2s[12];
#pragma unroll
    for (int kk = 0; kk < 3; ++kk)
#pragma unroll
      for (int g = 0; g < 4; ++g)
        w2s[kk * 4 + g] = W2v[((kk + (3 - kk0)) * 4 + g) * 512 + cg * 64 + l];

    // ---- layer 1 (heavy waves only): matmul + pointwise + h1 write ----
    if (hv) {
      float b1v[4];
#pragma unroll
      for (int g = 0; g < 4; ++g) b1v[g] = BIA[g * 64 + wq * 16 + col];
      short8 aA0 = *(const short8*)&A1r[a1rd +      quad * 8];
      short8 aA1 = *(const short8*)&A1r[a1rd + 32 + quad * 8];
      short8 aA2 = *(const short8*)&A1r[a1rd + 64 + quad * 8];
      f32x4 g1[4];
#pragma unroll
      for (int g = 0; g < 4; ++g) {
        f32x4 acc = (f32x4){b1v[g], b1v[g], b1v[g], b1v[g]};
        acc = MFMA16(aA0, *(const short8*)&W1L[(((0 * 4 + quad) << 8) + g * 64 + wq * 16 + col) * 8], acc);
        acc = MFMA16(aA1, *(const short8*)&W1L[(((1 * 4 + quad) << 8) + g * 64 + wq * 16 + col) * 8], acc);
        acc = MFMA16(aA2, *(const short8*)&W1L[(((2 * 4 + quad) << 8) + g * 64 + wq * 16 + col) * 8], acc);
        g1[g] = acc;
      }
      float h1v[4];
#pragma unroll
      for (int i = 0; i < 4; ++i)
        lstm_elem(g1[0][i], g1[1][i], g1[2][i], g1[3][i], c1a[i], h1v[i]);
      int base = (mh * 16 + quad * 4) * 104 + 32 + wq * 16 + col;
      unsigned pkA = cvt_pk_bf16(h1v[0], h1v[1]);
      unsigned pkB = cvt_pk_bf16(h1v[2], h1v[3]);
      A1w[base]       = (short)pkA;
      A1w[base + 104] = (short)(pkA >> 16);
      A1w[base + 208] = (short)pkB;
      A1w[base + 312] = (short)(pkB >> 16);
    }
    if (do_x)
      *(unsigned*)&A1w[xr * 104 + xi] = cvt_pk_bf16(xv.x, xv.y);

    // ---- layer 2 matmul: rows m2*16..+15, cols cg*16..+15, all 4 gates ----
    f32x4 g2[4];
    {
      float b2v[4];
#pragma unroll
      for (int g = 0; g < 4; ++g) b2v[g] = BIA[256 + g * 128 + u2];
#pragma unroll
      for (int g = 0; g < 4; ++g)
        g2[g] = (f32x4){b2v[g], b2v[g], b2v[g], b2v[g]};
    }
    const int arow = (m2 * 16 + col);
    // in-register kk half first
#pragma unroll
    for (int kk = 0; kk < 3; ++kk) {
      int kka = kk + kk0;
      short8 a0;
      if (kka < 2) a0 = *(const short8*)&A1r[arow * 104 + 32 + kka * 32 + quad * 8];
      else         a0 = *(const short8*)&A2r[arow * 136 + (kka - 2) * 32 + quad * 8];
#pragma unroll
      for (int g = 0; g < 4; ++g)
        g2[g] = MFMA16(a0, w2h[kk * 4 + g], g2[g]);
    }
    // streamed kk half
#pragma unroll
    for (int kk = 0; kk < 3; ++kk) {
      int kka = kk + (3 - kk0);
      short8 a0;
      if (kka < 2) a0 = *(const short8*)&A1r[arow * 104 + 32 + kka * 32 + quad * 8];
      else         a0 = *(const short8*)&A2r[arow * 136 + (kka - 2) * 32 + quad * 8];
#pragma unroll
      for (int g = 0; g < 4; ++g)
        g2[g] = MFMA16(a0, w2s[kk * 4 + g], g2[g]);
    }

    // ---- layer 2 pointwise: 4 elems -> h2 write (+fp32 on last step) ----
    {
      float hv4[4];
#pragma unroll
      for (int i = 0; i < 4; ++i)
        lstm_elem(g2[0][i], g2[1][i], g2[2][i], g2[3][i], c2r[i], hv4[i]);
      unsigned pkA = cvt_pk_bf16(hv4[0], hv4[1]);
      unsigned pkB = cvt_pk_bf16(hv4[2], hv4[3]);
      int base = (m2 * 16 + quad * 4) * 136 + u2;
      A2w[base]       = (short)pkA;
      A2w[base + 136] = (short)(pkA >> 16);
      A2w[base + 272] = (short)pkB;
      A2w[base + 408] = (short)(pkB >> 16);
      if (last) {
#pragma unroll
        for (int i = 0; i < 4; ++i)
          H2F[(m2 * 16 + quad * 4 + i) * 132 + u2] = hv4[i];
      }
    }
  };

  short* const A1_0 = A1b;            short* const A1_1 = A1b + 3328;
  short* const A2_0 = A2b;            short* const A2_1 = A2b + 4352;

  // ---- j=0 peeled: layer1 only (h1_0), x_1 by light waves ----
  {
    float2 xv;
    if (xln) xv = *(const float2*)xptr;
    if (hv) {
      float b1v[4];
#pragma unroll
      for (int g = 0; g < 4; ++g) b1v[g] = BIA[g * 64 + wq * 16 + col];
      short8 aA0 = *(const short8*)&A1_0[a1rd +      quad * 8];
      short8 aA1 = *(const short8*)&A1_0[a1rd + 32 + quad * 8];
      short8 aA2 = *(const short8*)&A1_0[a1rd + 64 + quad * 8];
      f32x4 g1[4];
#pragma unroll
      for (int g = 0; g < 4; ++g) {
        f32x4 acc = (f32x4){b1v[g], b1v[g], b1v[g], b1v[g]};
        acc = MFMA16(aA0, *(const short8*)&W1L[(((0 * 4 + quad) << 8) + g * 64 + wq * 16 + col) * 8], acc);
        acc = MFMA16(aA1, *(const short8*)&W1L[(((1 * 4 + quad) << 8) + g * 64 + wq * 16 + col) * 8], acc);
        acc = MFMA16(aA2, *(const short8*)&W1L[(((2 * 4 + quad) << 8) + g * 64 + wq * 16 + col) * 8], acc);
        g1[g] = acc;
      }
      float h1v[4];
#pragma unroll
      for (int i = 0; i < 4; ++i)
        lstm_elem(g1[0][i], g1[1][i], g1[2][i], g1[3][i], c1a[i], h1v[i]);
      int base = (mh * 16 + quad * 4) * 104 + 32 + wq * 16 + col;
      unsigned pkA = cvt_pk_bf16(h1v[0], h1v[1]);
      unsigned pkB = cvt_pk_bf16(h1v[2], h1v[3]);
      A1_1[base]       = (short)pkA;
      A1_1[base + 104] = (short)(pkA >> 16);
      A1_1[base + 208] = (short)pkB;
      A1_1[base + 312] = (short)(pkB >> 16);
    }
    if (xln)
      *(unsigned*)&A1_1[xr * 104 + xi] = cvt_pk_bf16(xv.x, xv.y);
    __syncthreads();
    xptr += 24;
  }

  // ---- main loop: j = 1..100, unrolled x2 (buffer roles compile-time) ----
  for (int jj = 1; jj <= 99; jj += 2) {
    step(A1_1, A2_1, A1_0, A2_0, jj <= 98, false);
    __syncthreads();
    xptr += 24;
    step(A1_0, A2_0, A1_1, A2_1, jj + 1 <= 98, jj + 1 == 100);
    __syncthreads();
    xptr += 24;
  }

  // ---- head (fp32). H2F holds h2_99; scratch aliases the W1L region ----
  float* const FC1W = (float*)(pool + 16896);
  float* const FC2W = (float*)(pool + 20992);
  float* const FB1  = (float*)(pool + 21248);
  float* const FB2  = (float*)(pool + 21280);
  float* const OWp  = (float*)(pool + 21312);
  float* const OBp  = (float*)(pool + 21344);
  float* const X1   = (float*)(pool + 21376);
  float* const X2   = (float*)(pool + 22400);

  if (tid < 1024) FC1W[tid] = p.WF[768 + tid];
  if (tid < 64)               FC2W[tid]     = p.WF[1792 + tid];
  if (tid >= 64 && tid < 72)  FB1[tid - 64] = p.WF[1856 + tid - 64];
  if (tid >= 72 && tid < 80)  FB2[tid - 72] = p.WF[1864 + tid - 72];
  if (tid >= 80 && tid < 88)  OWp[tid - 80] = p.WF[1872 + tid - 80];
  if (tid == 88)              OBp[0]        = p.WF[1880];
  __syncthreads();

  if (tid < 256) {
    int row = tid >> 3, o = tid & 7;
    float s = FB1[o];
#pragma unroll 8
    for (int k = 0; k < 128; ++k) s += H2F[row * 132 + k] * FC1W[o * 128 + k];
    X1[tid] = fmaxf(s, 0.0f);
  }
  __syncthreads();
  if (tid < 256) {
    int row = tid >> 3, o = tid & 7;
    float s = FB2[o];
#pragma unroll
    for (int k = 0; k < 8; ++k) s += X1[row * 8 + k] * FC2W[o * 8 + k];
    X2[tid] = fmaxf(s, 0.0f);
  }
  __syncthreads();
  if (tid < 32) {
    float s = OBp[0];
#pragma unroll
    for (int k = 0; k < 8; ++k) s += X2[tid * 8 + k] * OWp[k];
    p.out[b0 + tid] = s;
  }
}

extern "C" void kernel_launch(void* const* d_in, const int* in_sizes, int n_in,
                              void* d_out, int out_size, void* d_ws, size_t ws_size,
                              hipStream_t stream)
{
  (void)in_sizes; (void)n_in; (void)ws_size; (void)out_size;

  SampParams sp;
  const float** grp[12] = { sp.w1i, sp.w1h, sp.b1, sp.w2i, sp.w2h, sp.b2,
                            sp.f1w, sp.f1b, sp.f2w, sp.f2b, sp.ow, sp.ob };
  int idx = 1;
  for (int t = 0; t < 12; ++t)
    for (int j = 0; j < 3; ++j)
      grp[t][j] = (const float*)d_in[idx++];
  sp.W2S = (short*)d_ws;
  sp.W1G = (short*)((char*)d_ws + WS_W1G_OFF);
  sp.WF  = (float*)((char*)d_ws + WS_WF_OFF);

  LstmParams bp;
  bp.input = (const float*)d_in[0];
  bp.W2S = (const short*)d_ws;
  bp.W1G = (const short*)((char*)d_ws + WS_W1G_OFF);
  bp.WF  = (const float*)((char*)d_ws + WS_WF_OFF);
  bp.out = (float*)d_out;

  sample_kernel<<<dim3(68), dim3(256), 0, stream>>>(sp);
  blstm_kernel<<<dim3(256), dim3(1024), 0, stream>>>(bp);
}

// Round 8
// 407.026 us; speedup vs baseline: 2.5281x; 2.5281x over previous
//
#include <hip/hip_runtime.h>
#include <math.h>

// Bayesian 2-layer LSTM (B=8192,T=100,I=24,H=64,H2=128) — two-kernel version.
//
// R13: exact R8 base (286 us verified; R9-R12 all regressed and are fully
// reverted) + ONE change: instruction-region reorder inside step().
//   R8 order:  L1mm -> L1pw(trans) -> L2mm -> L2pw(trans)
//   R13 order: L1mm -> L2mm -> L1pw -> writes -> L2pw -> writes
// L2mm reads only prev-step state (independent of L1pw), so this is a pure
// reorder. Each wave now presents one long MFMA region (60 MFMAs) and one
// long trans region -> the 2 waves/SIMD de-phase across pipes (one in MFMA
// while the other is in trans) instead of colliding region-by-region.
// Structural facts locked in by R11/R12: W2-in-regs pins 2 waves/SIMD;
// any occupancy raise spills (WRITE_SIZE tripwire) or streams (FETCH tripwire).

typedef __attribute__((ext_vector_type(8))) short short8;   // 8 bf16
typedef __attribute__((ext_vector_type(4))) float f32x4;

#define MFMA16(a, b, c) __builtin_amdgcn_mfma_f32_16x16x32_bf16((a), (b), (c), 0, 0, 0)

// ---- d_ws layout (bytes) ----
// [0, 196608)        W2S : 12288 short8 frags, idx = (kk*4+g)*512 + tid
// [196608, 245760)   W1G : 3072 short8, u = slice*256+n (slice = kk*4+quad)
// [245760, 253284)   WF  : 1881 floats: b1[256] b2[512] fc1w[1024] fc2w[64]
//                          fc1b[8] fc2b[8] ow[8] ob[1]
#define WS_W1G_OFF 196608
#define WS_WF_OFF  245760

struct SampParams {
  const float* w1i[3]; const float* w1h[3]; const float* b1[3];
  const float* w2i[3]; const float* w2h[3]; const float* b2[3];
  const float* f1w[3]; const float* f1b[3];
  const float* f2w[3]; const float* f2b[3];
  const float* ow[3];  const float* ob[3];
  short* W2S; short* W1G; float* WF;
};

struct LstmParams {
  const float* input;
  const short* W2S; const short* W1G; const float* WF;
  float* out;
};

__device__ __forceinline__ float softplus_fast(float x) {
  // log(1+e^x) = ln2 * log2(1 + 2^(x*log2e))
  float e = __builtin_amdgcn_exp2f(1.44269504f * x);
  return 0.69314718f * __builtin_amdgcn_logf(1.0f + e);
}

__device__ __forceinline__ float samp(const float* const q[3], int idx) {
  return q[0][idx] + softplus_fast(q[1][idx]) * q[2][idx];
}

__device__ __forceinline__ short f2bf(float f) {
  unsigned u = __float_as_uint(f);
  unsigned r = (u + 0x7FFFu + ((u >> 16) & 1u)) >> 16;   // RNE
  return (short)r;
}

__device__ __forceinline__ unsigned cvt_pk_bf16(float lo, float hi) {
  unsigned r;
  asm("v_cvt_pk_bf16_f32 %0, %1, %2" : "=v"(r) : "v"(lo), "v"(hi));
  return r;
}

// One LSTM element: gates (i,f,g,o) -> new cell c, hidden h.
// All activations are rcp(1+exp2(k*x)); reciprocals paired:
// rcp(A)&rcp(B) via r=rcp(A*B): 1/A=r*B, 1/B=r*A.  5 exp2 + 3 rcp.  (R8)
__device__ __forceinline__ void lstm_elem(float gi, float gf, float gg, float go,
                                          float& c, float& h) {
  float A = 1.0f + __builtin_amdgcn_exp2f(-1.44269504f * gi);   // 1/A = sig(i)
  float B = 1.0f + __builtin_amdgcn_exp2f(-1.44269504f * gf);   // 1/B = sig(f)
  float r = __builtin_amdgcn_rcpf(A * B);
  float si = r * B;
  float sf = r * A;
  float C = 1.0f + __builtin_amdgcn_exp2f(2.88539008f * gg);    // tanh(g)=1-2/C
  float D = 1.0f + __builtin_amdgcn_exp2f(-1.44269504f * go);   // 1/D = sig(o)
  float r2 = __builtin_amdgcn_rcpf(C * D);
  float tg = 1.0f - 2.0f * (r2 * D);
  float so = r2 * C;
  float cn = sf * c + si * tg;
  c = cn;
  float E = 1.0f + __builtin_amdgcn_exp2f(2.88539008f * cn);
  h = so * (1.0f - 2.0f * __builtin_amdgcn_rcpf(E));
}

// ---------------- kernel 1: sample all weights into d_ws ----------------
__global__ __launch_bounds__(256) void sample_kernel(SampParams p)
{
  int i = blockIdx.x * 256 + threadIdx.x;
  if (i < 12288) {
    int tid = i & 511, gg = (i >> 9) & 3, kk = i >> 11;
    int quad = (tid >> 4) & 3, col = tid & 15, v0 = (tid >> 6) * 16;
    int c = gg * 128 + v0 + col;
    short8 v;
#pragma unroll
    for (int j = 0; j < 8; ++j) {
      int k = kk * 32 + quad * 8 + j;
      float x = (k < 64) ? samp(p.w2i, k * 512 + c) : samp(p.w2h, (k - 64) * 512 + c);
      v[j] = f2bf(x);
    }
    *(short8*)&p.W2S[i * 8] = v;
  } else if (i < 15360) {
    int u = i - 12288;
    int slice = u >> 8, n = u & 255;
    int k0 = (slice >> 2) * 32 + (slice & 3) * 8;
    short8 v;
#pragma unroll
    for (int j = 0; j < 8; ++j) {
      int k = k0 + j;
      float x = 0.0f;
      if (k < 24)       x = samp(p.w1i, k * 256 + n);
      else if (k >= 32) x = samp(p.w1h, (k - 32) * 256 + n);
      v[j] = f2bf(x);
    }
    *(short8*)&p.W1G[u * 8] = v;
  } else if (i < 17241) {
    int u = i - 15360;
    float x;
    if (u < 256)       x = samp(p.b1,  u);
    else if (u < 768)  x = samp(p.b2,  u - 256);
    else if (u < 1792) x = samp(p.f1w, u - 768);
    else if (u < 1856) x = samp(p.f2w, u - 1792);
    else if (u < 1864) x = samp(p.f1b, u - 1856);
    else if (u < 1872) x = samp(p.f2b, u - 1864);
    else if (u < 1880) x = samp(p.ow,  u - 1872);
    else               x = samp(p.ob,  0);
    p.WF[u] = x;
  }
}

// ---------------- kernel 2: fused 2-layer LSTM + head ----------------
// LDS pool:
//   [0,49152)      W1L : W1cat bf16 (3072 short8)
//   [49152,62464)  A1  : 2 buf x (32 x 104 shorts) [x(24)|pad(8)|h1(64)]
//   [62464,79872)  A2  : 2 buf x (32 x 136 shorts) [h2(128)|pad]
// Head phase aliases [0,...) : H2 32x132 f32, FC1W, FC2W, FB1/FB2/OW/OB, X1, X2

__global__ __launch_bounds__(512, 2)
void blstm_kernel(LstmParams p)
{
  __shared__ __align__(16) unsigned char pool[79872];
  short* const W1L = (short*)pool;
  short* const A1b = (short*)(pool + 49152);   // 2 x 3328 shorts
  short* const A2b = (short*)(pool + 62464);   // 2 x 4352 shorts

  const int tid  = threadIdx.x;
  const int w    = tid >> 6;
  const int l    = tid & 63;
  const int quad = l >> 4;
  const int col  = l & 15;
  const int b0   = blockIdx.x * 32;

  const int wq = w & 3;             // layer1: n-group
  const int mh = w >> 2;            // layer1: m-half
  const int v0 = w * 16;            // layer2: unit base

  // W2 -> persistent registers/AGPRs (24 short8 = 96 regs). Occupancy is
  // grid-capped at 2 waves/SIMD, so regs up to 256 cost nothing.
  const short8* const W2v = (const short8*)p.W2S;
  short8 w2r[24];
#pragma unroll
  for (int f = 0; f < 24; ++f) w2r[f] = W2v[f * 512 + tid];

  // W1 global -> LDS (48 KB)
#pragma unroll
  for (int r = 0; r < 6; ++r) {
    short8 v = *(const short8*)&p.W1G[(r * 512 + tid) * 8];
    *(short8*)&W1L[(r * 512 + tid) * 8] = v;
  }

  float b1v[4], b2v[4];
#pragma unroll
  for (int g = 0; g < 4; ++g) b1v[g] = p.WF[g * 64 + wq * 16 + col];
#pragma unroll
  for (int g = 0; g < 4; ++g) b2v[g] = p.WF[256 + g * 128 + v0 + col];

  for (int i = tid; i < 6656; i += 512) A1b[i] = 0;   // both A1 buffers
  for (int i = tid; i < 8704; i += 512) A2b[i] = 0;   // both A2 buffers
  __syncthreads();

  // x_0 -> A1 buf0; hoisted per-thread x addressing (xr,xi loop-invariant)
  int xr = 0, xi = 0;
  const bool xln = tid < 384;
  const float* xptr = p.input;
  if (xln) {
    int e = tid * 2; xr = e / 24; xi = e - xr * 24;
    const float* base = p.input + (size_t)(b0 + xr) * 2400 + xi;
    float2 xv0 = *(const float2*)base;
    *(unsigned*)&A1b[xr * 104 + xi] = cvt_pk_bf16(xv0.x, xv0.y);
    xptr = base + 24;                 // -> x_1
  }
  __syncthreads();

  float c1a[4]    = {0.f, 0.f, 0.f, 0.f};
  float c2a[2][4] = {{0.f,0.f,0.f,0.f},{0.f,0.f,0.f,0.f}};
  float hf2[2][4];

  const int a1rd = (mh * 16 + col) * 104;

  // Full step, REORDERED: L1 matmul -> L2 matmul (both read only prev-state)
  // -> L1 pointwise + h1/x writes -> L2 pointwise + h2 writes.
  auto step = [&](const short* __restrict__ A1r, const short* __restrict__ A2r,
                  short* __restrict__ A1w, short* __restrict__ A2w, bool dox) {
    const bool do_x = dox && xln;
    float2 xv;
    if (do_x) xv = *(const float2*)xptr;   // x_{j+1}

    // ---- layer 1 matmul: gates1 ----
    short8 aA0 = *(const short8*)&A1r[a1rd +      quad * 8];
    short8 aA1 = *(const short8*)&A1r[a1rd + 32 + quad * 8];
    short8 aA2 = *(const short8*)&A1r[a1rd + 64 + quad * 8];
    f32x4 g1[4];
#pragma unroll
    for (int g = 0; g < 4; ++g) {
      f32x4 acc = (f32x4){b1v[g], b1v[g], b1v[g], b1v[g]};
      acc = MFMA16(aA0, *(const short8*)&W1L[(((0 * 4 + quad) << 8) + g * 64 + wq * 16 + col) * 8], acc);
      acc = MFMA16(aA1, *(const short8*)&W1L[(((1 * 4 + quad) << 8) + g * 64 + wq * 16 + col) * 8], acc);
      acc = MFMA16(aA2, *(const short8*)&W1L[(((2 * 4 + quad) << 8) + g * 64 + wq * 16 + col) * 8], acc);
      g1[g] = acc;
    }

    // ---- layer 2 matmul: gates2 (independent of L1 pointwise) ----
    f32x4 g2[2][4];
#pragma unroll
    for (int g = 0; g < 4; ++g) {
      g2[0][g] = (f32x4){b2v[g], b2v[g], b2v[g], b2v[g]};
      g2[1][g] = g2[0][g];
    }
#pragma unroll
    for (int kk = 0; kk < 6; ++kk) {
      short8 a0, a1f;
      if (kk < 2) {
        a0  = *(const short8*)&A1r[      col  * 104 + 32 + kk * 32 + quad * 8];
        a1f = *(const short8*)&A1r[(16 + col) * 104 + 32 + kk * 32 + quad * 8];
      } else {
        int o = (kk - 2) * 32 + quad * 8;
        a0  = *(const short8*)&A2r[      col  * 136 + o];
        a1f = *(const short8*)&A2r[(16 + col) * 136 + o];
      }
#pragma unroll
      for (int g = 0; g < 4; ++g) {
        g2[0][g] = MFMA16(a0,  w2r[kk * 4 + g], g2[0][g]);
        g2[1][g] = MFMA16(a1f, w2r[kk * 4 + g], g2[1][g]);
      }
    }

    // ---- layer 1 pointwise -> h1 into next buffer ----
    {
      float h1v[4];
#pragma unroll
      for (int i = 0; i < 4; ++i)
        lstm_elem(g1[0][i], g1[1][i], g1[2][i], g1[3][i], c1a[i], h1v[i]);
      int base = (mh * 16 + quad * 4) * 104 + 32 + wq * 16 + col;
      unsigned pkA = cvt_pk_bf16(h1v[0], h1v[1]);
      unsigned pkB = cvt_pk_bf16(h1v[2], h1v[3]);
      A1w[base]       = (short)pkA;
      A1w[base + 104] = (short)(pkA >> 16);
      A1w[base + 208] = (short)pkB;
      A1w[base + 312] = (short)(pkB >> 16);
    }
    if (do_x)
      *(unsigned*)&A1w[xr * 104 + xi] = cvt_pk_bf16(xv.x, xv.y);

    // ---- layer 2 pointwise -> h2 into next buffer ----
    {
      int u2 = v0 + col;
#pragma unroll
      for (int mi = 0; mi < 2; ++mi) {
        float hv[4];
#pragma unroll
        for (int i = 0; i < 4; ++i) {
          lstm_elem(g2[mi][0][i], g2[mi][1][i], g2[mi][2][i], g2[mi][3][i],
                    c2a[mi][i], hv[i]);
          hf2[mi][i] = hv[i];
        }
        unsigned pkA = cvt_pk_bf16(hv[0], hv[1]);
        unsigned pkB = cvt_pk_bf16(hv[2], hv[3]);
        int base = (mi * 16 + quad * 4) * 136 + u2;
        A2w[base]       = (short)pkA;
        A2w[base + 136] = (short)(pkA >> 16);
        A2w[base + 272] = (short)pkB;
        A2w[base + 408] = (short)(pkB >> 16);
      }
    }
  };

  short* const A1_0 = A1b;            short* const A1_1 = A1b + 3328;
  short* const A2_0 = A2b;            short* const A2_1 = A2b + 4352;

  // ---- j=0 peeled: layer1 only (h1_0), x_1 prefetch; L2 state is zeros ----
  {
    float2 xv;
    if (xln) xv = *(const float2*)xptr;
    short8 aA0 = *(const short8*)&A1_0[a1rd +      quad * 8];
    short8 aA1 = *(const short8*)&A1_0[a1rd + 32 + quad * 8];
    short8 aA2 = *(const short8*)&A1_0[a1rd + 64 + quad * 8];
    f32x4 g1[4];
#pragma unroll
    for (int g = 0; g < 4; ++g) {
      f32x4 acc = (f32x4){b1v[g], b1v[g], b1v[g], b1v[g]};
      acc = MFMA16(aA0, *(const short8*)&W1L[(((0 * 4 + quad) << 8) + g * 64 + wq * 16 + col) * 8], acc);
      acc = MFMA16(aA1, *(const short8*)&W1L[(((1 * 4 + quad) << 8) + g * 64 + wq * 16 + col) * 8], acc);
      acc = MFMA16(aA2, *(const short8*)&W1L[(((2 * 4 + quad) << 8) + g * 64 + wq * 16 + col) * 8], acc);
      g1[g] = acc;
    }
    float h1v[4];
#pragma unroll
    for (int i = 0; i < 4; ++i)
      lstm_elem(g1[0][i], g1[1][i], g1[2][i], g1[3][i], c1a[i], h1v[i]);
    int base = (mh * 16 + quad * 4) * 104 + 32 + wq * 16 + col;
    unsigned pkA = cvt_pk_bf16(h1v[0], h1v[1]);
    unsigned pkB = cvt_pk_bf16(h1v[2], h1v[3]);
    A1_1[base]       = (short)pkA;
    A1_1[base + 104] = (short)(pkA >> 16);
    A1_1[base + 208] = (short)pkB;
    A1_1[base + 312] = (short)(pkB >> 16);
    if (xln)
      *(unsigned*)&A1_1[xr * 104 + xi] = cvt_pk_bf16(xv.x, xv.y);
    __syncthreads();
    xptr += 24;
  }

  // ---- main loop: j = 1..100, unrolled x2 (buffer roles compile-time) ----
  for (int jj = 1; jj <= 99; jj += 2) {
    // j = jj (odd): read buf1, write buf0
    step(A1_1, A2_1, A1_0, A2_0, jj <= 98);
    __syncthreads();
    xptr += 24;
    // j = jj+1 (even): read buf0, write buf1
    step(A1_0, A2_0, A1_1, A2_1, jj + 1 <= 98);
    __syncthreads();
    xptr += 24;
  }

  // ---- head (fp32), aliased over W1L region ----
  float* const H2   = (float*)pool;                 // 32 x 132
  float* const FC1W = (float*)(pool + 16896);
  float* const FC2W = (float*)(pool + 20992);
  float* const FB1  = (float*)(pool + 21248);
  float* const FB2  = (float*)(pool + 21280);
  float* const OWp  = (float*)(pool + 21312);
  float* const OBp  = (float*)(pool + 21344);
  float* const X1   = (float*)(pool + 21376);
  float* const X2   = (float*)(pool + 22400);

  {
    int u2 = v0 + col;
#pragma unroll
    for (int mi = 0; mi < 2; ++mi)
#pragma unroll
      for (int i = 0; i < 4; ++i) {
        int row = mi * 16 + quad * 4 + i;
        H2[row * 132 + u2] = hf2[mi][i];   // h2_99
      }
  }
  for (int i = tid; i < 1024; i += 512) FC1W[i] = p.WF[768 + i];
  if (tid < 64)               FC2W[tid]     = p.WF[1792 + tid];
  if (tid >= 64 && tid < 72)  FB1[tid - 64] = p.WF[1856 + tid - 64];
  if (tid >= 72 && tid < 80)  FB2[tid - 72] = p.WF[1864 + tid - 72];
  if (tid >= 80 && tid < 88)  OWp[tid - 80] = p.WF[1872 + tid - 80];
  if (tid == 88)              OBp[0]        = p.WF[1880];
  __syncthreads();

  if (tid < 256) {
    int row = tid >> 3, o = tid & 7;
    float s = FB1[o];
#pragma unroll 8
    for (int k = 0; k < 128; ++k) s += H2[row * 132 + k] * FC1W[o * 128 + k];
    X1[tid] = fmaxf(s, 0.0f);
  }
  __syncthreads();
  if (tid < 256) {
    int row = tid >> 3, o = tid & 7;
    float s = FB2[o];
#pragma unroll
    for (int k = 0; k < 8; ++k) s += X1[row * 8 + k] * FC2W[o * 8 + k];
    X2[tid] = fmaxf(s, 0.0f);
  }
  __syncthreads();
  if (tid < 32) {
    float s = OBp[0];
#pragma unroll
    for (int k = 0; k < 8; ++k) s += X2[tid * 8 + k] * OWp[k];
    p.out[b0 + tid] = s;
  }
}

extern "C" void kernel_launch(void* const* d_in, const int* in_sizes, int n_in,
                              void* d_out, int out_size, void* d_ws, size_t ws_size,
                              hipStream_t stream)
{
  (void)in_sizes; (void)n_in; (void)ws_size; (void)out_size;

  SampParams sp;
  const float** grp[12] = { sp.w1i, sp.w1h, sp.b1, sp.w2i, sp.w2h, sp.b2,
                            sp.f1w, sp.f1b, sp.f2w, sp.f2b, sp.ow, sp.ob };
  int idx = 1;
  for (int t = 0; t < 12; ++t)
    for (int j = 0; j < 3; ++j)
      grp[t][j] = (const float*)d_in[idx++];
  sp.W2S = (short*)d_ws;
  sp.W1G = (short*)((char*)d_ws + WS_W1G_OFF);
  sp.WF  = (float*)((char*)d_ws + WS_WF_OFF);

  LstmParams bp;
  bp.input = (const float*)d_in[0];
  bp.W2S = (const short*)d_ws;
  bp.W1G = (const short*)((char*)d_ws + WS_W1G_OFF);
  bp.WF  = (const float*)((char*)d_ws + WS_WF_OFF);
  bp.out = (float*)d_out;

  sample_kernel<<<dim3(68), dim3(256), 0, stream>>>(sp);
  blstm_kernel<<<dim3(256), dim3(512), 0, stream>>>(bp);
}

// Round 9
// 399.786 us; speedup vs baseline: 2.5739x; 1.0181x over previous
//
#include <hip/hip_runtime.h>
#include <math.h>

// Bayesian 2-layer LSTM (B=8192,T=100,I=24,H=64,H2=128) — two-kernel version.
//
// R14 = exact R8 restoration (verified best: blstm 286.4 us, total 400.0 us).
// R9-R13 post-mortems (all regressed, all reverted):
//   R9  packed f32x2 + common-denominator pw: +4% (chain coupling)
//   R10 fused-rcp quad + asm lgkm-barrier:    +4% (trans latency-bound,
//       not issue-bound: 19% fewer trans, zero gain)
//   R11 W1->regs: spilled (WRITE_SIZE 32K->2.6MB tripwire)
//   R12 16-wave:  spilled + streamed W2 (FETCH 39MB->2.5GB tripwire)
//   R13 MFMA clustering: +3% (extended acc live ranges; R8's interleaved
//       order was already optimal for the scheduler)
// Structure pinned by: 202 serial phases; W2-in-regs => 2 waves/SIMD
// (any occupancy raise spills); trans-latency-bound VALU (60%).
//
// R8 = R6 control structure + paired-rcp lstm_elem (5 exp2 + 3 rcp) +
// v_cvt_pk_bf16_f32 packing + j=0 peel + x2-unrolled double-buffered loop
// (compile-time buffer roles), one __syncthreads per step.

typedef __attribute__((ext_vector_type(8))) short short8;   // 8 bf16
typedef __attribute__((ext_vector_type(4))) float f32x4;

#define MFMA16(a, b, c) __builtin_amdgcn_mfma_f32_16x16x32_bf16((a), (b), (c), 0, 0, 0)

// ---- d_ws layout (bytes) ----
// [0, 196608)        W2S : 12288 short8 frags, idx = (kk*4+g)*512 + tid
// [196608, 245760)   W1G : 3072 short8, u = slice*256+n (slice = kk*4+quad)
// [245760, 253284)   WF  : 1881 floats: b1[256] b2[512] fc1w[1024] fc2w[64]
//                          fc1b[8] fc2b[8] ow[8] ob[1]
#define WS_W1G_OFF 196608
#define WS_WF_OFF  245760

struct SampParams {
  const float* w1i[3]; const float* w1h[3]; const float* b1[3];
  const float* w2i[3]; const float* w2h[3]; const float* b2[3];
  const float* f1w[3]; const float* f1b[3];
  const float* f2w[3]; const float* f2b[3];
  const float* ow[3];  const float* ob[3];
  short* W2S; short* W1G; float* WF;
};

struct LstmParams {
  const float* input;
  const short* W2S; const short* W1G; const float* WF;
  float* out;
};

__device__ __forceinline__ float softplus_fast(float x) {
  // log(1+e^x) = ln2 * log2(1 + 2^(x*log2e))
  float e = __builtin_amdgcn_exp2f(1.44269504f * x);
  return 0.69314718f * __builtin_amdgcn_logf(1.0f + e);
}

__device__ __forceinline__ float samp(const float* const q[3], int idx) {
  return q[0][idx] + softplus_fast(q[1][idx]) * q[2][idx];
}

__device__ __forceinline__ short f2bf(float f) {
  unsigned u = __float_as_uint(f);
  unsigned r = (u + 0x7FFFu + ((u >> 16) & 1u)) >> 16;   // RNE
  return (short)r;
}

__device__ __forceinline__ unsigned cvt_pk_bf16(float lo, float hi) {
  unsigned r;
  asm("v_cvt_pk_bf16_f32 %0, %1, %2" : "=v"(r) : "v"(lo), "v"(hi));
  return r;
}

// One LSTM element: gates (i,f,g,o) -> new cell c, hidden h.
// All activations are rcp(1+exp2(k*x)); reciprocals paired:
// rcp(A)&rcp(B) via r=rcp(A*B): 1/A=r*B, 1/B=r*A.  5 exp2 + 3 rcp.
__device__ __forceinline__ void lstm_elem(float gi, float gf, float gg, float go,
                                          float& c, float& h) {
  float A = 1.0f + __builtin_amdgcn_exp2f(-1.44269504f * gi);   // 1/A = sig(i)
  float B = 1.0f + __builtin_amdgcn_exp2f(-1.44269504f * gf);   // 1/B = sig(f)
  float r = __builtin_amdgcn_rcpf(A * B);
  float si = r * B;
  float sf = r * A;
  float C = 1.0f + __builtin_amdgcn_exp2f(2.88539008f * gg);    // tanh(g)=1-2/C
  float D = 1.0f + __builtin_amdgcn_exp2f(-1.44269504f * go);   // 1/D = sig(o)
  float r2 = __builtin_amdgcn_rcpf(C * D);
  float tg = 1.0f - 2.0f * (r2 * D);
  float so = r2 * C;
  float cn = sf * c + si * tg;
  c = cn;
  float E = 1.0f + __builtin_amdgcn_exp2f(2.88539008f * cn);
  h = so * (1.0f - 2.0f * __builtin_amdgcn_rcpf(E));
}

// ---------------- kernel 1: sample all weights into d_ws ----------------
__global__ __launch_bounds__(256) void sample_kernel(SampParams p)
{
  int i = blockIdx.x * 256 + threadIdx.x;
  if (i < 12288) {
    int tid = i & 511, gg = (i >> 9) & 3, kk = i >> 11;
    int quad = (tid >> 4) & 3, col = tid & 15, v0 = (tid >> 6) * 16;
    int c = gg * 128 + v0 + col;
    short8 v;
#pragma unroll
    for (int j = 0; j < 8; ++j) {
      int k = kk * 32 + quad * 8 + j;
      float x = (k < 64) ? samp(p.w2i, k * 512 + c) : samp(p.w2h, (k - 64) * 512 + c);
      v[j] = f2bf(x);
    }
    *(short8*)&p.W2S[i * 8] = v;
  } else if (i < 15360) {
    int u = i - 12288;
    int slice = u >> 8, n = u & 255;
    int k0 = (slice >> 2) * 32 + (slice & 3) * 8;
    short8 v;
#pragma unroll
    for (int j = 0; j < 8; ++j) {
      int k = k0 + j;
      float x = 0.0f;
      if (k < 24)       x = samp(p.w1i, k * 256 + n);
      else if (k >= 32) x = samp(p.w1h, (k - 32) * 256 + n);
      v[j] = f2bf(x);
    }
    *(short8*)&p.W1G[u * 8] = v;
  } else if (i < 17241) {
    int u = i - 15360;
    float x;
    if (u < 256)       x = samp(p.b1,  u);
    else if (u < 768)  x = samp(p.b2,  u - 256);
    else if (u < 1792) x = samp(p.f1w, u - 768);
    else if (u < 1856) x = samp(p.f2w, u - 1792);
    else if (u < 1864) x = samp(p.f1b, u - 1856);
    else if (u < 1872) x = samp(p.f2b, u - 1864);
    else if (u < 1880) x = samp(p.ow,  u - 1872);
    else               x = samp(p.ob,  0);
    p.WF[u] = x;
  }
}

// ---------------- kernel 2: fused 2-layer LSTM + head ----------------
// LDS pool:
//   [0,49152)      W1L : W1cat bf16 (3072 short8)
//   [49152,62464)  A1  : 2 buf x (32 x 104 shorts) [x(24)|pad(8)|h1(64)]
//   [62464,79872)  A2  : 2 buf x (32 x 136 shorts) [h2(128)|pad]
// Head phase aliases [0,...) : H2 32x132 f32, FC1W, FC2W, FB1/FB2/OW/OB, X1, X2

__global__ __launch_bounds__(512, 2)
void blstm_kernel(LstmParams p)
{
  __shared__ __align__(16) unsigned char pool[79872];
  short* const W1L = (short*)pool;
  short* const A1b = (short*)(pool + 49152);   // 2 x 3328 shorts
  short* const A2b = (short*)(pool + 62464);   // 2 x 4352 shorts

  const int tid  = threadIdx.x;
  const int w    = tid >> 6;
  const int l    = tid & 63;
  const int quad = l >> 4;
  const int col  = l & 15;
  const int b0   = blockIdx.x * 32;

  const int wq = w & 3;             // layer1: n-group
  const int mh = w >> 2;            // layer1: m-half
  const int v0 = w * 16;            // layer2: unit base

  // W2 -> persistent registers/AGPRs (24 short8 = 96 regs). Occupancy is
  // grid-capped at 2 waves/SIMD, so regs up to 256 cost nothing.
  const short8* const W2v = (const short8*)p.W2S;
  short8 w2r[24];
#pragma unroll
  for (int f = 0; f < 24; ++f) w2r[f] = W2v[f * 512 + tid];

  // W1 global -> LDS (48 KB)
#pragma unroll
  for (int r = 0; r < 6; ++r) {
    short8 v = *(const short8*)&p.W1G[(r * 512 + tid) * 8];
    *(short8*)&W1L[(r * 512 + tid) * 8] = v;
  }

  float b1v[4], b2v[4];
#pragma unroll
  for (int g = 0; g < 4; ++g) b1v[g] = p.WF[g * 64 + wq * 16 + col];
#pragma unroll
  for (int g = 0; g < 4; ++g) b2v[g] = p.WF[256 + g * 128 + v0 + col];

  for (int i = tid; i < 6656; i += 512) A1b[i] = 0;   // both A1 buffers
  for (int i = tid; i < 8704; i += 512) A2b[i] = 0;   // both A2 buffers
  __syncthreads();

  // x_0 -> A1 buf0; hoisted per-thread x addressing (xr,xi loop-invariant)
  int xr = 0, xi = 0;
  const bool xln = tid < 384;
  const float* xptr = p.input;
  if (xln) {
    int e = tid * 2; xr = e / 24; xi = e - xr * 24;
    const float* base = p.input + (size_t)(b0 + xr) * 2400 + xi;
    float2 xv0 = *(const float2*)base;
    *(unsigned*)&A1b[xr * 104 + xi] = cvt_pk_bf16(xv0.x, xv0.y);
    xptr = base + 24;                 // -> x_1
  }
  __syncthreads();

  float c1a[4]    = {0.f, 0.f, 0.f, 0.f};
  float c2a[2][4] = {{0.f,0.f,0.f,0.f},{0.f,0.f,0.f,0.f}};
  float hf2[2][4];

  const int a1rd = (mh * 16 + col) * 104;

  // Full step: layer1 (gates1 on [x|h1_prev]) -> pointwise -> layer2
  // (gates2 on [h1_prev|h2_prev]) -> pointwise. Reads A1r/A2r, writes
  // A1w/A2w. All pointers compile-time constant at each call site.
  auto step = [&](const short* __restrict__ A1r, const short* __restrict__ A2r,
                  short* __restrict__ A1w, short* __restrict__ A2w, bool dox) {
    const bool do_x = dox && xln;
    float2 xv;
    if (do_x) xv = *(const float2*)xptr;   // x_{j+1}

    // ---- layer 1 matmul: gates1 ----
    short8 aA0 = *(const short8*)&A1r[a1rd +      quad * 8];
    short8 aA1 = *(const short8*)&A1r[a1rd + 32 + quad * 8];
    short8 aA2 = *(const short8*)&A1r[a1rd + 64 + quad * 8];
    f32x4 g1[4];
#pragma unroll
    for (int g = 0; g < 4; ++g) {
      f32x4 acc = (f32x4){b1v[g], b1v[g], b1v[g], b1v[g]};
      acc = MFMA16(aA0, *(const short8*)&W1L[(((0 * 4 + quad) << 8) + g * 64 + wq * 16 + col) * 8], acc);
      acc = MFMA16(aA1, *(const short8*)&W1L[(((1 * 4 + quad) << 8) + g * 64 + wq * 16 + col) * 8], acc);
      acc = MFMA16(aA2, *(const short8*)&W1L[(((2 * 4 + quad) << 8) + g * 64 + wq * 16 + col) * 8], acc);
      g1[g] = acc;
    }

    // ---- layer 1 pointwise -> h1 into next buffer ----
    {
      float h1v[4];
#pragma unroll
      for (int i = 0; i < 4; ++i)
        lstm_elem(g1[0][i], g1[1][i], g1[2][i], g1[3][i], c1a[i], h1v[i]);
      int base = (mh * 16 + quad * 4) * 104 + 32 + wq * 16 + col;
      unsigned pkA = cvt_pk_bf16(h1v[0], h1v[1]);
      unsigned pkB = cvt_pk_bf16(h1v[2], h1v[3]);
      A1w[base]       = (short)pkA;
      A1w[base + 104] = (short)(pkA >> 16);
      A1w[base + 208] = (short)pkB;
      A1w[base + 312] = (short)(pkB >> 16);
    }
    if (do_x)
      *(unsigned*)&A1w[xr * 104 + xi] = cvt_pk_bf16(xv.x, xv.y);

    // ---- layer 2 matmul: gates2 (B-operand from registers) ----
    f32x4 g2[2][4];
#pragma unroll
    for (int g = 0; g < 4; ++g) {
      g2[0][g] = (f32x4){b2v[g], b2v[g], b2v[g], b2v[g]};
      g2[1][g] = g2[0][g];
    }
#pragma unroll
    for (int kk = 0; kk < 6; ++kk) {
      short8 a0, a1f;
      if (kk < 2) {
        a0  = *(const short8*)&A1r[      col  * 104 + 32 + kk * 32 + quad * 8];
        a1f = *(const short8*)&A1r[(16 + col) * 104 + 32 + kk * 32 + quad * 8];
      } else {
        int o = (kk - 2) * 32 + quad * 8;
        a0  = *(const short8*)&A2r[      col  * 136 + o];
        a1f = *(const short8*)&A2r[(16 + col) * 136 + o];
      }
#pragma unroll
      for (int g = 0; g < 4; ++g) {
        g2[0][g] = MFMA16(a0,  w2r[kk * 4 + g], g2[0][g]);
        g2[1][g] = MFMA16(a1f, w2r[kk * 4 + g], g2[1][g]);
      }
    }

    // ---- layer 2 pointwise -> h2 into next buffer ----
    {
      int u2 = v0 + col;
#pragma unroll
      for (int mi = 0; mi < 2; ++mi) {
        float hv[4];
#pragma unroll
        for (int i = 0; i < 4; ++i) {
          lstm_elem(g2[mi][0][i], g2[mi][1][i], g2[mi][2][i], g2[mi][3][i],
                    c2a[mi][i], hv[i]);
          hf2[mi][i] = hv[i];
        }
        unsigned pkA = cvt_pk_bf16(hv[0], hv[1]);
        unsigned pkB = cvt_pk_bf16(hv[2], hv[3]);
        int base = (mi * 16 + quad * 4) * 136 + u2;
        A2w[base]       = (short)pkA;
        A2w[base + 136] = (short)(pkA >> 16);
        A2w[base + 272] = (short)pkB;
        A2w[base + 408] = (short)(pkB >> 16);
      }
    }
  };

  short* const A1_0 = A1b;            short* const A1_1 = A1b + 3328;
  short* const A2_0 = A2b;            short* const A2_1 = A2b + 4352;

  // ---- j=0 peeled: layer1 only (h1_0), x_1 prefetch; L2 state is zeros ----
  {
    float2 xv;
    if (xln) xv = *(const float2*)xptr;
    short8 aA0 = *(const short8*)&A1_0[a1rd +      quad * 8];
    short8 aA1 = *(const short8*)&A1_0[a1rd + 32 + quad * 8];
    short8 aA2 = *(const short8*)&A1_0[a1rd + 64 + quad * 8];
    f32x4 g1[4];
#pragma unroll
    for (int g = 0; g < 4; ++g) {
      f32x4 acc = (f32x4){b1v[g], b1v[g], b1v[g], b1v[g]};
      acc = MFMA16(aA0, *(const short8*)&W1L[(((0 * 4 + quad) << 8) + g * 64 + wq * 16 + col) * 8], acc);
      acc = MFMA16(aA1, *(const short8*)&W1L[(((1 * 4 + quad) << 8) + g * 64 + wq * 16 + col) * 8], acc);
      acc = MFMA16(aA2, *(const short8*)&W1L[(((2 * 4 + quad) << 8) + g * 64 + wq * 16 + col) * 8], acc);
      g1[g] = acc;
    }
    float h1v[4];
#pragma unroll
    for (int i = 0; i < 4; ++i)
      lstm_elem(g1[0][i], g1[1][i], g1[2][i], g1[3][i], c1a[i], h1v[i]);
    int base = (mh * 16 + quad * 4) * 104 + 32 + wq * 16 + col;
    unsigned pkA = cvt_pk_bf16(h1v[0], h1v[1]);
    unsigned pkB = cvt_pk_bf16(h1v[2], h1v[3]);
    A1_1[base]       = (short)pkA;
    A1_1[base + 104] = (short)(pkA >> 16);
    A1_1[base + 208] = (short)pkB;
    A1_1[base + 312] = (short)(pkB >> 16);
    if (xln)
      *(unsigned*)&A1_1[xr * 104 + xi] = cvt_pk_bf16(xv.x, xv.y);
    __syncthreads();
    xptr += 24;
  }

  // ---- main loop: j = 1..100, unrolled x2 (buffer roles compile-time) ----
  for (int jj = 1; jj <= 99; jj += 2) {
    // j = jj (odd): read buf1, write buf0
    step(A1_1, A2_1, A1_0, A2_0, jj <= 98);
    __syncthreads();
    xptr += 24;
    // j = jj+1 (even): read buf0, write buf1
    step(A1_0, A2_0, A1_1, A2_1, jj + 1 <= 98);
    __syncthreads();
    xptr += 24;
  }

  // ---- head (fp32), aliased over W1L region ----
  float* const H2   = (float*)pool;                 // 32 x 132
  float* const FC1W = (float*)(pool + 16896);
  float* const FC2W = (float*)(pool + 20992);
  float* const FB1  = (float*)(pool + 21248);
  float* const FB2  = (float*)(pool + 21280);
  float* const OWp  = (float*)(pool + 21312);
  float* const OBp  = (float*)(pool + 21344);
  float* const X1   = (float*)(pool + 21376);
  float* const X2   = (float*)(pool + 22400);

  {
    int u2 = v0 + col;
#pragma unroll
    for (int mi = 0; mi < 2; ++mi)
#pragma unroll
      for (int i = 0; i < 4; ++i) {
        int row = mi * 16 + quad * 4 + i;
        H2[row * 132 + u2] = hf2[mi][i];   // h2_99
      }
  }
  for (int i = tid; i < 1024; i += 512) FC1W[i] = p.WF[768 + i];
  if (tid < 64)               FC2W[tid]     = p.WF[1792 + tid];
  if (tid >= 64 && tid < 72)  FB1[tid - 64] = p.WF[1856 + tid - 64];
  if (tid >= 72 && tid < 80)  FB2[tid - 72] = p.WF[1864 + tid - 72];
  if (tid >= 80 && tid < 88)  OWp[tid - 80] = p.WF[1872 + tid - 80];
  if (tid == 88)              OBp[0]        = p.WF[1880];
  __syncthreads();

  if (tid < 256) {
    int row = tid >> 3, o = tid & 7;
    float s = FB1[o];
#pragma unroll 8
    for (int k = 0; k < 128; ++k) s += H2[row * 132 + k] * FC1W[o * 128 + k];
    X1[tid] = fmaxf(s, 0.0f);
  }
  __syncthreads();
  if (tid < 256) {
    int row = tid >> 3, o = tid & 7;
    float s = FB2[o];
#pragma unroll
    for (int k = 0; k < 8; ++k) s += X1[row * 8 + k] * FC2W[o * 8 + k];
    X2[tid] = fmaxf(s, 0.0f);
  }
  __syncthreads();
  if (tid < 32) {
    float s = OBp[0];
#pragma unroll
    for (int k = 0; k < 8; ++k) s += X2[tid * 8 + k] * OWp[k];
    p.out[b0 + tid] = s;
  }
}

extern "C" void kernel_launch(void* const* d_in, const int* in_sizes, int n_in,
                              void* d_out, int out_size, void* d_ws, size_t ws_size,
                              hipStream_t stream)
{
  (void)in_sizes; (void)n_in; (void)ws_size; (void)out_size;

  SampParams sp;
  const float** grp[12] = { sp.w1i, sp.w1h, sp.b1, sp.w2i, sp.w2h, sp.b2,
                            sp.f1w, sp.f1b, sp.f2w, sp.f2b, sp.ow, sp.ob };
  int idx = 1;
  for (int t = 0; t < 12; ++t)
    for (int j = 0; j < 3; ++j)
      grp[t][j] = (const float*)d_in[idx++];
  sp.W2S = (short*)d_ws;
  sp.W1G = (short*)((char*)d_ws + WS_W1G_OFF);
  sp.WF  = (float*)((char*)d_ws + WS_WF_OFF);

  LstmParams bp;
  bp.input = (const float*)d_in[0];
  bp.W2S = (const short*)d_ws;
  bp.W1G = (const short*)((char*)d_ws + WS_W1G_OFF);
  bp.WF  = (const float*)((char*)d_ws + WS_WF_OFF);
  bp.out = (float*)d_out;

  sample_kernel<<<dim3(68), dim3(256), 0, stream>>>(sp);
  blstm_kernel<<<dim3(256), dim3(512), 0, stream>>>(bp);
}